// Round 1
// baseline (1491.800 us; speedup 1.0000x reference)
//
#include <hip/hip_runtime.h>
#include <hip/hip_bf16.h>
#include <stdint.h>

#define IN_DIM   4096
#define OUT_DIM  11008
#define M_DIM    8192      // B*S = 4*2048

typedef unsigned short u16;
typedef __bf16 bf16_t;
typedef bf16_t bf16x8 __attribute__((ext_vector_type(8)));
typedef float  f32x4  __attribute__((ext_vector_type(4)));
typedef u16    u16x8  __attribute__((ext_vector_type(8)));

static __device__ __forceinline__ u16 f2bf(float f) {
    __bf16 h = (__bf16)f;                    // fptrunc = round-to-nearest-even
    return __builtin_bit_cast(unsigned short, h);
}

// global -> LDS async copy, 16B per lane; lds must be the WAVE-UNIFORM base
// (HW writes to base + lane*16), gaddr is per-lane.
static __device__ __forceinline__ void async_copy16(void* lds_uniform, const void* gaddr) {
    __builtin_amdgcn_global_load_lds(
        (const __attribute__((address_space(1))) uint32_t*)(uintptr_t)gaddr,
        (__attribute__((address_space(3))) uint32_t*)(uintptr_t)lds_uniform,
        16, 0, 0);
}

// ---------------- prep kernels ----------------

// x (fp32) -> bf16, 8 elems/thread
__global__ void qx_kernel(const float4* __restrict__ x, u16x8* __restrict__ xb, int n8) {
    int i = blockIdx.x * blockDim.x + threadIdx.x;
    if (i >= n8) return;
    float4 a = x[2 * i];
    float4 b = x[2 * i + 1];
    u16x8 r;
    r[0] = f2bf(a.x); r[1] = f2bf(a.y); r[2] = f2bf(a.z); r[3] = f2bf(a.w);
    r[4] = f2bf(b.x); r[5] = f2bf(b.y); r[6] = f2bf(b.z); r[7] = f2bf(b.w);
    xb[i] = r;
}

// w (fp32) -> bf16(+-s), group of 128 flat elems shares s = max(|scale[g]|, 1e-8)
__global__ void qw_kernel(const float* __restrict__ w, const float* __restrict__ scale,
                          u16x8* __restrict__ wb, int n8) {
    int i = blockIdx.x * blockDim.x + threadIdx.x;
    if (i >= n8) return;
    int g = i >> 4;                                    // (i*8)/128
    float s = fmaxf(fabsf(scale[g]), 1e-8f);
    u16 bs = f2bf(s);
    const float4* p = (const float4*)(w) + 2 * (size_t)i;
    float4 a = p[0];
    float4 b = p[1];
    u16x8 r;
    r[0] = bs | ((a.x < 0.f) ? 0x8000 : 0);
    r[1] = bs | ((a.y < 0.f) ? 0x8000 : 0);
    r[2] = bs | ((a.z < 0.f) ? 0x8000 : 0);
    r[3] = bs | ((a.w < 0.f) ? 0x8000 : 0);
    r[4] = bs | ((b.x < 0.f) ? 0x8000 : 0);
    r[5] = bs | ((b.y < 0.f) ? 0x8000 : 0);
    r[6] = bs | ((b.z < 0.f) ? 0x8000 : 0);
    r[7] = bs | ((b.w < 0.f) ? 0x8000 : 0);
    wb[i] = r;
}

// ---------------- GEMM: C[M][N] = A[M][K] * B[N][K]^T + bias ----------------
// 128x128 tile, BK=64, 256 threads = 4 waves, each wave 64x64 (4x4 of 16x16x32).
// LDS chunk-XOR swizzle: LDS[row][c] holds global chunk (c ^ (row&7)).

__global__ __launch_bounds__(256) void gemm_kernel(const u16* __restrict__ A,
                                                   const u16* __restrict__ Bw,
                                                   const float* __restrict__ bias,
                                                   float* __restrict__ out) {
    __shared__ __align__(16) u16 sA[128 * 64];
    __shared__ __align__(16) u16 sB[128 * 64];

    const int tid  = threadIdx.x;
    const int w    = tid >> 6;
    const int lane = tid & 63;
    const int m0   = blockIdx.y * 128;
    const int n0   = blockIdx.x * 128;
    const int wm   = (w & 1) * 64;    // wave tile origin within block tile
    const int wn   = (w >> 1) * 64;

    // staging: per wave 4 instrs/tile, each covers 8 rows x 128B
    const int lrow   = lane >> 3;           // 0..7 within 8-row slab
    const int lcol   = lane & 7;            // LDS chunk within row
    const int gchunk = lcol ^ lrow;         // swizzle: row&7 == lrow here
    const u16* gA[4];
    const u16* gB[4];
    u16* lA[4];
    u16* lB[4];
#pragma unroll
    for (int t = 0; t < 4; ++t) {
        int row = w * 32 + t * 8 + lrow;
        gA[t] = A  + (size_t)(m0 + row) * IN_DIM + gchunk * 8;
        gB[t] = Bw + (size_t)(n0 + row) * IN_DIM + gchunk * 8;
        lA[t] = &sA[(w * 4 + t) * 512];     // 1KB slab, wave-uniform
        lB[t] = &sB[(w * 4 + t) * 512];
    }

    f32x4 acc[4][4];
#pragma unroll
    for (int mt = 0; mt < 4; ++mt)
#pragma unroll
        for (int nt = 0; nt < 4; ++nt)
            acc[mt][nt] = (f32x4){0.f, 0.f, 0.f, 0.f};

    const int row16 = lane & 15;
    const int quad  = lane >> 4;

    for (int it = 0; it < IN_DIM / 64; ++it) {
#pragma unroll
        for (int t = 0; t < 4; ++t) {
            async_copy16(lA[t], gA[t]);
            async_copy16(lB[t], gB[t]);
            gA[t] += 64;
            gB[t] += 64;
        }
        __syncthreads();   // drains vmcnt (global_load_lds) + barrier

#pragma unroll
        for (int ks = 0; ks < 2; ++ks) {
            const int c = ks * 4 + quad;   // global chunk this quad reads
            bf16x8 af[4], bfr[4];
#pragma unroll
            for (int mt = 0; mt < 4; ++mt) {
                int row = wm + mt * 16 + row16;
                af[mt] = *(const bf16x8*)&sA[row * 64 + ((c ^ (row & 7)) * 8)];
            }
#pragma unroll
            for (int nt = 0; nt < 4; ++nt) {
                int row = wn + nt * 16 + row16;
                bfr[nt] = *(const bf16x8*)&sB[row * 64 + ((c ^ (row & 7)) * 8)];
            }
#pragma unroll
            for (int mt = 0; mt < 4; ++mt)
#pragma unroll
                for (int nt = 0; nt < 4; ++nt)
                    acc[mt][nt] = __builtin_amdgcn_mfma_f32_16x16x32_bf16(
                        af[mt], bfr[nt], acc[mt][nt], 0, 0, 0);
        }
        __syncthreads();
    }

    // epilogue: C/D layout col = lane&15, row = quad*4 + reg
#pragma unroll
    for (int nt = 0; nt < 4; ++nt) {
        int col  = n0 + wn + nt * 16 + row16;
        float bv = bias[col];
#pragma unroll
        for (int mt = 0; mt < 4; ++mt) {
            int row = m0 + wm + mt * 16 + quad * 4;
            float* po = out + (size_t)row * OUT_DIM + col;
#pragma unroll
            for (int r = 0; r < 4; ++r)
                po[(size_t)r * OUT_DIM] = acc[mt][nt][r] + bv;
        }
    }
}

// ---------------- emergency fallback (ws too small): slow but correct ----------------
__global__ void naive_kernel(const float* __restrict__ x, const float* __restrict__ wt,
                             const float* __restrict__ bias, const float* __restrict__ scale,
                             float* __restrict__ out) {
    long idx = (long)blockIdx.x * 256 + threadIdx.x;
    if (idx >= (long)M_DIM * OUT_DIM) return;
    int m = (int)(idx / OUT_DIM);
    int o = (int)(idx % OUT_DIM);
    const float* xr = x + (size_t)m * IN_DIM;
    const float* wr = wt + (size_t)o * IN_DIM;
    float acc = 0.f;
    for (int gb = 0; gb < IN_DIM / 128; ++gb) {
        float s = fmaxf(fabsf(scale[o * (IN_DIM / 128) + gb]), 1e-8f);
        float part = 0.f;
        for (int k = 0; k < 128; ++k) {
            float wv = wr[gb * 128 + k];
            part += (wv >= 0.f) ? xr[gb * 128 + k] : -xr[gb * 128 + k];
        }
        acc += part * s;
    }
    out[idx] = acc + bias[o];
}

extern "C" void kernel_launch(void* const* d_in, const int* in_sizes, int n_in,
                              void* d_out, int out_size, void* d_ws, size_t ws_size,
                              hipStream_t stream) {
    const float* x     = (const float*)d_in[0];
    const float* wt    = (const float*)d_in[1];
    const float* bias  = (const float*)d_in[2];
    const float* scale = (const float*)d_in[3];
    float* out = (float*)d_out;

    const size_t xb_bytes = (size_t)M_DIM * IN_DIM * sizeof(u16);     // 67 MB
    const size_t wb_bytes = (size_t)OUT_DIM * IN_DIM * sizeof(u16);   // 90 MB

    if (ws_size >= xb_bytes + wb_bytes) {
        u16* xb = (u16*)d_ws;
        u16* wb = (u16*)((char*)d_ws + xb_bytes);

        int nx8 = (M_DIM * IN_DIM) / 8;
        qx_kernel<<<nx8 / 256, 256, 0, stream>>>((const float4*)x, (u16x8*)xb, nx8);

        int nw8 = (OUT_DIM * IN_DIM) / 8;
        qw_kernel<<<nw8 / 256, 256, 0, stream>>>(wt, scale, (u16x8*)wb, nw8);

        dim3 grid(OUT_DIM / 128, M_DIM / 128);   // 86 x 64
        gemm_kernel<<<grid, 256, 0, stream>>>(xb, wb, bias, out);
    } else {
        long total = (long)M_DIM * OUT_DIM;
        int blocks = (int)((total + 255) / 256);
        naive_kernel<<<blocks, 256, 0, stream>>>(x, wt, bias, scale, out);
    }
}

// Round 2
// 1305.968 us; speedup vs baseline: 1.1423x; 1.1423x over previous
//
#include <hip/hip_runtime.h>
#include <hip/hip_bf16.h>
#include <stdint.h>

#define IN_DIM   4096
#define OUT_DIM  11008
#define M_DIM    8192      // B*S = 4*2048

typedef unsigned short u16;
typedef __bf16 bf16_t;
typedef bf16_t bf16x8 __attribute__((ext_vector_type(8)));
typedef float  f32x4  __attribute__((ext_vector_type(4)));
typedef u16    u16x8  __attribute__((ext_vector_type(8)));

static __device__ __forceinline__ u16 f2bf(float f) {
    __bf16 h = (__bf16)f;                    // fptrunc = round-to-nearest-even
    return __builtin_bit_cast(unsigned short, h);
}

// global -> LDS async copy, 16B per lane; lds must be the WAVE-UNIFORM base
// (HW writes to base + lane*16), gaddr is per-lane.
static __device__ __forceinline__ void async_copy16(void* lds_uniform, const void* gaddr) {
    __builtin_amdgcn_global_load_lds(
        (const __attribute__((address_space(1))) uint32_t*)(uintptr_t)gaddr,
        (__attribute__((address_space(3))) uint32_t*)(uintptr_t)lds_uniform,
        16, 0, 0);
}

// ---------------- fused prep kernel ----------------
// blocks [0, XB_BLOCKS): cast x fp32 -> bf16, 8 elems/thread
// blocks [XB_BLOCKS, ..): w fp32 -> bf16(+-s), group of 128 shares s
#define XB_BLOCKS ((M_DIM * IN_DIM / 8) / 256)          // 16384
#define WB_BLOCKS ((OUT_DIM * IN_DIM / 8) / 256)        // 22016

__global__ void prep_kernel(const float* __restrict__ x, const float* __restrict__ w,
                            const float* __restrict__ scale,
                            u16x8* __restrict__ xb, u16x8* __restrict__ wb) {
    if (blockIdx.x < XB_BLOCKS) {
        int i = blockIdx.x * 256 + threadIdx.x;
        const float4* p = (const float4*)x + 2 * (size_t)i;
        float4 a = p[0];
        float4 b = p[1];
        u16x8 r;
        r[0] = f2bf(a.x); r[1] = f2bf(a.y); r[2] = f2bf(a.z); r[3] = f2bf(a.w);
        r[4] = f2bf(b.x); r[5] = f2bf(b.y); r[6] = f2bf(b.z); r[7] = f2bf(b.w);
        xb[i] = r;
    } else {
        int i = (blockIdx.x - XB_BLOCKS) * 256 + threadIdx.x;
        int g = i >> 4;                                    // (i*8)/128
        float s = fmaxf(fabsf(scale[g]), 1e-8f);
        u16 bs = f2bf(s);
        const float4* p = (const float4*)w + 2 * (size_t)i;
        float4 a = p[0];
        float4 b = p[1];
        u16x8 r;
        r[0] = bs | ((a.x < 0.f) ? 0x8000 : 0);
        r[1] = bs | ((a.y < 0.f) ? 0x8000 : 0);
        r[2] = bs | ((a.z < 0.f) ? 0x8000 : 0);
        r[3] = bs | ((a.w < 0.f) ? 0x8000 : 0);
        r[4] = bs | ((b.x < 0.f) ? 0x8000 : 0);
        r[5] = bs | ((b.y < 0.f) ? 0x8000 : 0);
        r[6] = bs | ((b.z < 0.f) ? 0x8000 : 0);
        r[7] = bs | ((b.w < 0.f) ? 0x8000 : 0);
        wb[i] = r;
    }
}

// ---------------- GEMM: C[M][N] = A[M][K] * B[N][K]^T + bias ----------------
// 128x128 tile, BK=64, 256 threads = 4 waves, each wave 64x64 (4x4 of 16x16x32).
// LDS chunk-XOR swizzle: LDS[row][c] holds global chunk (c ^ (row&7)).
// Grid: 1-D, group-M=16 serpentine swizzle for L2/L3 locality.

#define NPID_M (M_DIM / 128)     // 64
#define NPID_N (OUT_DIM / 128)   // 86
#define GROUP_M 16

__global__ __launch_bounds__(256) void gemm_kernel(const u16* __restrict__ A,
                                                   const u16* __restrict__ Bw,
                                                   const float* __restrict__ bias,
                                                   float* __restrict__ out) {
    __shared__ __align__(16) u16 sA[128 * 64];
    __shared__ __align__(16) u16 sB[128 * 64];

    // group-M swizzle: 16 consecutive blocks share one B tile (different A rows)
    const int pid       = blockIdx.x;
    const int per_group = GROUP_M * NPID_N;            // 1376
    const int group     = pid / per_group;
    const int pin       = pid - group * per_group;
    const int pid_m     = group * GROUP_M + (pin & (GROUP_M - 1));
    const int pid_n     = pin >> 4;                    // pin / GROUP_M

    const int tid  = threadIdx.x;
    const int w    = tid >> 6;
    const int lane = tid & 63;
    const int m0   = pid_m * 128;
    const int n0   = pid_n * 128;
    const int wm   = (w & 1) * 64;    // wave tile origin within block tile
    const int wn   = (w >> 1) * 64;

    // staging: per wave 4 instrs/tile, each covers 8 rows x 128B
    const int lrow   = lane >> 3;           // 0..7 within 8-row slab
    const int lcol   = lane & 7;            // LDS chunk within row
    const int gchunk = lcol ^ lrow;         // swizzle: row&7 == lrow here
    const u16* gA[4];
    const u16* gB[4];
    u16* lA[4];
    u16* lB[4];
#pragma unroll
    for (int t = 0; t < 4; ++t) {
        int row = w * 32 + t * 8 + lrow;
        gA[t] = A  + (size_t)(m0 + row) * IN_DIM + gchunk * 8;
        gB[t] = Bw + (size_t)(n0 + row) * IN_DIM + gchunk * 8;
        lA[t] = &sA[(w * 4 + t) * 512];     // 1KB slab, wave-uniform
        lB[t] = &sB[(w * 4 + t) * 512];
    }

    f32x4 acc[4][4];
#pragma unroll
    for (int mt = 0; mt < 4; ++mt)
#pragma unroll
        for (int nt = 0; nt < 4; ++nt)
            acc[mt][nt] = (f32x4){0.f, 0.f, 0.f, 0.f};

    const int row16 = lane & 15;
    const int quad  = lane >> 4;

    for (int it = 0; it < IN_DIM / 64; ++it) {
#pragma unroll
        for (int t = 0; t < 4; ++t) {
            async_copy16(lA[t], gA[t]);
            async_copy16(lB[t], gB[t]);
            gA[t] += 64;
            gB[t] += 64;
        }
        __syncthreads();   // drains vmcnt (global_load_lds) + barrier

#pragma unroll
        for (int ks = 0; ks < 2; ++ks) {
            const int c = ks * 4 + quad;   // global chunk this quad reads
            bf16x8 af[4], bfr[4];
#pragma unroll
            for (int mt = 0; mt < 4; ++mt) {
                int row = wm + mt * 16 + row16;
                af[mt] = *(const bf16x8*)&sA[row * 64 + ((c ^ (row & 7)) * 8)];
            }
#pragma unroll
            for (int nt = 0; nt < 4; ++nt) {
                int row = wn + nt * 16 + row16;
                bfr[nt] = *(const bf16x8*)&sB[row * 64 + ((c ^ (row & 7)) * 8)];
            }
#pragma unroll
            for (int mt = 0; mt < 4; ++mt)
#pragma unroll
                for (int nt = 0; nt < 4; ++nt)
                    acc[mt][nt] = __builtin_amdgcn_mfma_f32_16x16x32_bf16(
                        af[mt], bfr[nt], acc[mt][nt], 0, 0, 0);
        }
        __syncthreads();
    }

    // epilogue: C/D layout col = lane&15, row = quad*4 + reg
    // nontemporal stores: don't let the 360 MB output stream evict B tiles from L2
#pragma unroll
    for (int nt = 0; nt < 4; ++nt) {
        int col  = n0 + wn + nt * 16 + row16;
        float bv = bias[col];
#pragma unroll
        for (int mt = 0; mt < 4; ++mt) {
            int row = m0 + wm + mt * 16 + quad * 4;
            float* po = out + (size_t)row * OUT_DIM + col;
#pragma unroll
            for (int r = 0; r < 4; ++r)
                __builtin_nontemporal_store(acc[mt][nt][r] + bv, po + (size_t)r * OUT_DIM);
        }
    }
}

// ---------------- emergency fallback (ws too small): slow but correct ----------------
__global__ void naive_kernel(const float* __restrict__ x, const float* __restrict__ wt,
                             const float* __restrict__ bias, const float* __restrict__ scale,
                             float* __restrict__ out) {
    long idx = (long)blockIdx.x * 256 + threadIdx.x;
    if (idx >= (long)M_DIM * OUT_DIM) return;
    int m = (int)(idx / OUT_DIM);
    int o = (int)(idx % OUT_DIM);
    const float* xr = x + (size_t)m * IN_DIM;
    const float* wr = wt + (size_t)o * IN_DIM;
    float acc = 0.f;
    for (int gb = 0; gb < IN_DIM / 128; ++gb) {
        float s = fmaxf(fabsf(scale[o * (IN_DIM / 128) + gb]), 1e-8f);
        float part = 0.f;
        for (int k = 0; k < 128; ++k) {
            float wv = wr[gb * 128 + k];
            part += (wv >= 0.f) ? xr[gb * 128 + k] : -xr[gb * 128 + k];
        }
        acc += part * s;
    }
    out[idx] = acc + bias[o];
}

extern "C" void kernel_launch(void* const* d_in, const int* in_sizes, int n_in,
                              void* d_out, int out_size, void* d_ws, size_t ws_size,
                              hipStream_t stream) {
    const float* x     = (const float*)d_in[0];
    const float* wt    = (const float*)d_in[1];
    const float* bias  = (const float*)d_in[2];
    const float* scale = (const float*)d_in[3];
    float* out = (float*)d_out;

    const size_t xb_bytes = (size_t)M_DIM * IN_DIM * sizeof(u16);     // 67 MB
    const size_t wb_bytes = (size_t)OUT_DIM * IN_DIM * sizeof(u16);   // 90 MB

    if (ws_size >= xb_bytes + wb_bytes) {
        u16* xb = (u16*)d_ws;
        u16* wb = (u16*)((char*)d_ws + xb_bytes);

        prep_kernel<<<XB_BLOCKS + WB_BLOCKS, 256, 0, stream>>>(
            x, wt, scale, (u16x8*)xb, (u16x8*)wb);

        gemm_kernel<<<NPID_M * NPID_N, 256, 0, stream>>>(xb, wb, bias, out);
    } else {
        long total = (long)M_DIM * OUT_DIM;
        int blocks = (int)((total + 255) / 256);
        naive_kernel<<<blocks, 256, 0, stream>>>(x, wt, bias, scale, out);
    }
}